// Round 4
// baseline (1026.533 us; speedup 1.0000x reference)
//
#include <hip/hip_runtime.h>

#define TT 4096
#define HD 2048
#define FD 768
#define NE 32
#define TOPK 4
#define NSG 8
#define CAPE 1024
#define MAXTILES 160
#define UPGRID (MAXTILES * 6)
#define DNGRID (MAXTILES * 16)

typedef __attribute__((ext_vector_type(8))) short short8;
typedef __attribute__((ext_vector_type(4))) float f32x4;
typedef __attribute__((ext_vector_type(4))) unsigned short us4;
typedef __attribute__((ext_vector_type(8))) unsigned short us8;

__device__ __forceinline__ unsigned short f2bf(float f) {
  unsigned u = __builtin_bit_cast(unsigned, f);
  u += 0x7FFFu + ((u >> 16) & 1u);
  return (unsigned short)(u >> 16);
}

__device__ __forceinline__ void async16(const void* g, void* l) {
  __builtin_amdgcn_global_load_lds(
      (const __attribute__((address_space(1))) unsigned int*)g,
      (__attribute__((address_space(3))) unsigned int*)l, 16, 0, 0);
}

// ---------------- w_router [H][E] -> wrt [E][H] (fp32, tiny) ----------------
__global__ __launch_bounds__(256) void wrt_kernel(const float* __restrict__ w_router,
                                                  float* __restrict__ wrt) {
  int idx = blockIdx.x * 256 + threadIdx.x;
  int e = idx >> 11, h = idx & 2047;
  wrt[idx] = w_router[h * NE + e];
}

// ---------------- logits fp32 GEMM: [TT,HD] x [HD,NE] -> [TT,NE] ----------------
#define LSTR 68
__global__ __launch_bounds__(256) void logits_kernel(
    const float* __restrict__ rin, const float* __restrict__ wrt,
    float* __restrict__ logits) {
  __shared__ float As[16 * LSTR];
  __shared__ float Bs[32 * LSTR];
  const int tid = threadIdx.x;
  const int t0 = blockIdx.x * 16;
  const int tp = tid >> 4, eg = tid & 15;
  f32x4 acc0 = (f32x4)0.f, acc1 = (f32x4)0.f;
  for (int kt = 0; kt < HD; kt += 64) {
    __syncthreads();
    {
      int row = tid >> 4, col = (tid & 15) * 4;
      *(f32x4*)&As[row * LSTR + col] =
          *(const f32x4*)&rin[(size_t)(t0 + row) * HD + kt + col];
    }
    {
      int e = tid >> 3, col = (tid & 7) * 8;
      *(f32x4*)&Bs[e * LSTR + col] = *(const f32x4*)&wrt[(size_t)e * HD + kt + col];
      *(f32x4*)&Bs[e * LSTR + col + 4] =
          *(const f32x4*)&wrt[(size_t)e * HD + kt + col + 4];
    }
    __syncthreads();
#pragma unroll
    for (int k4 = 0; k4 < 16; ++k4) {
      f32x4 a = *(const f32x4*)&As[tp * LSTR + k4 * 4];
      f32x4 b0 = *(const f32x4*)&Bs[eg * LSTR + k4 * 4];
      f32x4 b1 = *(const f32x4*)&Bs[(eg + 16) * LSTR + k4 * 4];
      acc0 += a * b0;
      acc1 += a * b1;
    }
  }
  logits[(t0 + tp) * NE + eg] = acc0[0] + acc0[1] + acc0[2] + acc0[3];
  logits[(t0 + tp) * NE + eg + 16] = acc1[0] + acc1[1] + acc1[2] + acc1[3];
}

// ---------------- top-4 + softmax per token ----------------
__global__ __launch_bounds__(256) void topk_kernel(
    const float* __restrict__ logits, float* __restrict__ top_logits,
    int* __restrict__ sel, float* __restrict__ rwts) {
  __shared__ float lg[256 * 33];
  const int tid = threadIdx.x;
  const int t0 = blockIdx.x * 256;
#pragma unroll
  for (int i = 0; i < 8; ++i) {
    int fi = tid + i * 256;
    f32x4 v = *(const f32x4*)&logits[(size_t)t0 * NE + fi * 4];
    int tok = fi >> 3, e0 = (fi & 7) * 4;
#pragma unroll
    for (int c = 0; c < 4; ++c) lg[tok * 33 + e0 + c] = v[c];
  }
  __syncthreads();
  const float* row = &lg[tid * 33];
  float val[TOPK];
  int idx[TOPK];
  unsigned used = 0;
#pragma unroll
  for (int k = 0; k < TOPK; ++k) {
    float best = -1e30f;
    int bi = 0;
    for (int e = 0; e < NE; ++e) {
      float v = row[e];
      if (!((used >> e) & 1u) && v > best) { best = v; bi = e; }
    }
    used |= 1u << bi;
    val[k] = best;
    idx[k] = bi;
  }
  float ex[TOPK], sum = 0.f;
#pragma unroll
  for (int k = 0; k < TOPK; ++k) { ex[k] = expf(val[k] - val[0]); sum += ex[k]; }
  int t = t0 + tid;
#pragma unroll
  for (int k = 0; k < TOPK; ++k) {
    top_logits[t * TOPK + k] = val[k];
    sel[t * TOPK + k] = idx[k];
    rwts[t * TOPK + k] = ex[k] / sum;
  }
}

// ---------------- dispatch: ordered compaction per expert ----------------
__global__ __launch_bounds__(256) void dispatch_kernel(
    const int* __restrict__ sel, const float* __restrict__ rwts,
    int* __restrict__ tok_idx, float* __restrict__ tok_w, int* __restrict__ counts) {
  const int e = blockIdx.x;
  __shared__ int wcnt[4];
  __shared__ int base;
  const int tid = threadIdx.x, lane = tid & 63, wid = tid >> 6;
  if (tid == 0) base = 0;
  __syncthreads();
  for (int t0 = 0; t0 < TT; t0 += 256) {
    int t = t0 + tid;
    int hitk = -1;
#pragma unroll
    for (int k = 0; k < TOPK; ++k)
      if (sel[t * TOPK + k] == e) hitk = k;
    unsigned long long m = __ballot(hitk >= 0);
    if (lane == 0) wcnt[wid] = __popcll(m);
    __syncthreads();
    int off = base;
    for (int w = 0; w < wid; ++w) off += wcnt[w];
    int pos = off + __popcll(m & ((1ULL << lane) - 1ULL));
    if (hitk >= 0 && pos < CAPE) {
      tok_idx[e * CAPE + pos] = t;
      tok_w[e * CAPE + pos] = rwts[t * TOPK + hitk];
    }
    __syncthreads();
    if (tid == 0) base += wcnt[0] + wcnt[1] + wcnt[2] + wcnt[3];
    __syncthreads();
  }
  if (tid == 0) counts[e] = base < CAPE ? base : CAPE;
}

// ---------------- tile work-list builder (deterministic order) ----------------
__global__ void build_tiles_kernel(const int* __restrict__ counts,
                                   int* __restrict__ tlist, int* __restrict__ ntiles) {
  if (threadIdx.x == 0) {
    int n = 0;
    for (int e = 0; e < NE; ++e) {
      int c = counts[e];
      int mb = (c + 127) >> 7;
      for (int m = 0; m < mb; ++m) tlist[n++] = (e << 8) | m;
    }
    ntiles[0] = n;
  }
}

// ---------------- secondary gate per (expert, slot) ----------------
__global__ __launch_bounds__(256) void sgate_kernel(
    const float* __restrict__ rin, const float* __restrict__ w_sgate,
    const int* __restrict__ tok_idx, const int* __restrict__ counts,
    unsigned* __restrict__ sgbits) {
  const int e = blockIdx.y;
  const int count = counts[e];
  const int s0 = blockIdx.x * 128;
  if (s0 >= count || count == 0) return;
  __shared__ float wsgS[2048 * 9];
  const int tid = threadIdx.x, lane = tid & 63, wid = tid >> 6;
  const float* wsg = w_sgate + (size_t)e * (HD * NSG);
#pragma unroll
  for (int p = 0; p < 8; ++p) {
    int row = p * 256 + tid;
    f32x4 v0 = *(const f32x4*)&wsg[row * 8];
    f32x4 v1 = *(const f32x4*)&wsg[row * 8 + 4];
#pragma unroll
    for (int c = 0; c < 4; ++c) {
      wsgS[row * 9 + c] = v0[c];
      wsgS[row * 9 + 4 + c] = v1[c];
    }
  }
  __syncthreads();
  const int base = s0 + wid * 32;
  for (int j = 0; j < 16; ++j) {
    int sA = base + j, sB = base + j + 16;
    if (sA >= count) break;
    int tokA = tok_idx[e * CAPE + sA];
    int tokB = tok_idx[e * CAPE + (sB < count ? sB : sA)];
    float zA[8], zB[8];
#pragma unroll
    for (int s = 0; s < 8; ++s) { zA[s] = 0.f; zB[s] = 0.f; }
    const float* rAp = rin + (size_t)tokA * HD;
    const float* rBp = rin + (size_t)tokB * HD;
#pragma unroll 4
    for (int i = 0; i < 32; ++i) {
      int h = lane + 64 * i;
      float rA = rAp[h];
      float rB = rBp[h];
#pragma unroll
      for (int s = 0; s < 8; ++s) {
        float w = wsgS[h * 9 + s];
        zA[s] += rA * w;
        zB[s] += rB * w;
      }
    }
#pragma unroll
    for (int s = 0; s < 8; ++s) {
#pragma unroll
      for (int d = 1; d < 64; d <<= 1) {
        zA[s] += __shfl_xor(zA[s], d);
        zB[s] += __shfl_xor(zB[s], d);
      }
    }
    if (lane == 0) {
      unsigned bA = 0, bB = 0;
#pragma unroll
      for (int s = 0; s < 8; ++s) {
        bA |= ((unsigned)(zA[s] > 0.f)) << s;
        bB |= ((unsigned)(zB[s] > 0.f)) << s;
      }
      sgbits[e * CAPE + sA] = bA;
      if (sB < count) sgbits[e * CAPE + sB] = bB;
    }
  }
}

// ---------------- prepass: x fp32 -> bf16 ----------------
__global__ __launch_bounds__(256) void cvt_x_kernel(const float* __restrict__ x,
                                                    unsigned short* __restrict__ xb) {
  size_t i = ((size_t)blockIdx.x * 256 + threadIdx.x) * 8;
  float4 a = *(const float4*)(x + i);
  float4 b = *(const float4*)(x + i + 4);
  us8 o = {f2bf(a.x), f2bf(a.y), f2bf(a.z), f2bf(a.w),
           f2bf(b.x), f2bf(b.y), f2bf(b.z), f2bf(b.w)};
  *(us8*)(xb + i) = o;
}

// ---------------- prepass: per-expert transpose+convert in[R][C] f32 -> out[C][R] bf16 ---
__global__ __launch_bounds__(256) void transpose_cvt_kernel(
    const float* __restrict__ in, unsigned short* __restrict__ out, int R, int C) {
  const int e = blockIdx.z;
  const int r0 = blockIdx.x * 64, c0 = blockIdx.y * 64;
  __shared__ float t[64][65];
  const int tid = threadIdx.x;
  const float* inp = in + (size_t)e * R * C;
  {
    const int row = tid >> 4, col4 = (tid & 15) << 2;
#pragma unroll
    for (int p = 0; p < 4; ++p) {
      float4 v = *(const float4*)(inp + (size_t)(r0 + p * 16 + row) * C + c0 + col4);
      t[p * 16 + row][col4 + 0] = v.x;
      t[p * 16 + row][col4 + 1] = v.y;
      t[p * 16 + row][col4 + 2] = v.z;
      t[p * 16 + row][col4 + 3] = v.w;
    }
  }
  __syncthreads();
  {
    const int c = tid >> 2, j = tid & 3;
    us8 o0, o1;
#pragma unroll
    for (int i = 0; i < 8; ++i) o0[i] = f2bf(t[j * 16 + i][c]);
#pragma unroll
    for (int i = 0; i < 8; ++i) o1[i] = f2bf(t[j * 16 + 8 + i][c]);
    unsigned short* op = out + (size_t)e * R * C + (size_t)(c0 + c) * R + r0 + j * 16;
    *(us8*)op = o0;
    *(us8*)(op + 8) = o1;
  }
}

// ---------------- up/gate GEMM (bf16, async staging, work-list) ----------------
__global__ __launch_bounds__(256, 3) void up_gate_bf16(
    const unsigned short* __restrict__ xb, const unsigned short* __restrict__ wub,
    const unsigned short* __restrict__ wgb, const int* __restrict__ tok_idx,
    const int* __restrict__ counts, const unsigned* __restrict__ sgbits,
    const int* __restrict__ tlist, const int* __restrict__ ntiles,
    unsigned short* __restrict__ act) {
  // XCD-chunk swizzle: keep a tile's 6 n-blocks on one XCD
  const int hw = blockIdx.x;
  const int idx = (hw & 7) * (UPGRID / 8) + (hw >> 3);
  const int ti = idx / 6, nb = idx - ti * 6;
  if (ti >= ntiles[0]) return;
  const int entry = tlist[ti];
  const int e = entry >> 8;
  const int m0 = (entry & 255) << 7;
  const int n0 = nb * 128;
  const int count = counts[e];

  __shared__ __align__(16) unsigned short As[128 * 64];
  __shared__ __align__(16) unsigned short Bu[128 * 64];
  __shared__ __align__(16) unsigned short Bg[128 * 64];

  const int tid = threadIdx.x, lane = tid & 63, wid = tid >> 6;
  const int wr = wid >> 1, wc = wid & 1;
  const int ecap = e * CAPE;

  const int srow = tid >> 3, sblk = tid & 7;
  const unsigned short *gA[4], *gU[4], *gG[4];
#pragma unroll
  for (int c = 0; c < 4; ++c) {
    int r = c * 32 + srow;
    int gm = m0 + r;
    int gc = gm < count ? gm : count - 1;
    int swz = (sblk ^ (r & 7)) << 3;
    gA[c] = xb + (size_t)tok_idx[ecap + gc] * HD + swz;
    gU[c] = wub + (size_t)(e * FD + n0 + r) * HD + swz;
    gG[c] = wgb + (size_t)(e * FD + n0 + r) * HD + swz;
  }
  unsigned short* lA = As + (tid << 3);
  unsigned short* lU = Bu + (tid << 3);
  unsigned short* lG = Bg + (tid << 3);

  f32x4 accU[4][4], accG[4][4];
#pragma unroll
  for (int i = 0; i < 4; ++i)
#pragma unroll
    for (int j = 0; j < 4; ++j) { accU[i][j] = (f32x4)0.f; accG[i][j] = (f32x4)0.f; }

  const int fr = lane & 15, fq = lane >> 4;
  const int frx = (fr & 7) << 3;

  for (int kt = 0; kt < HD; kt += 64) {
    __syncthreads();
#pragma unroll
    for (int c = 0; c < 4; ++c) {
      async16(gA[c] + kt, lA + c * 2048);
      async16(gU[c] + kt, lU + c * 2048);
      async16(gG[c] + kt, lG + c * 2048);
    }
    __syncthreads();
#pragma unroll
    for (int kk = 0; kk < 64; kk += 32) {
      short8 af[4], bu[4], bg[4];
      const int kphys = (kk + fq * 8) ^ frx;
#pragma unroll
      for (int mi = 0; mi < 4; ++mi)
        af[mi] = *(const short8*)(As + ((wr * 64 + mi * 16 + fr) << 6) + kphys);
#pragma unroll
      for (int ni = 0; ni < 4; ++ni) {
        bu[ni] = *(const short8*)(Bu + ((wc * 64 + ni * 16 + fr) << 6) + kphys);
        bg[ni] = *(const short8*)(Bg + ((wc * 64 + ni * 16 + fr) << 6) + kphys);
      }
#pragma unroll
      for (int mi = 0; mi < 4; ++mi)
#pragma unroll
        for (int ni = 0; ni < 4; ++ni) {
          accU[mi][ni] = __builtin_amdgcn_mfma_f32_16x16x32_bf16(af[mi], bu[ni], accU[mi][ni], 0, 0, 0);
          accG[mi][ni] = __builtin_amdgcn_mfma_f32_16x16x32_bf16(af[mi], bg[ni], accG[mi][ni], 0, 0, 0);
        }
    }
  }
#pragma unroll
  for (int mi = 0; mi < 4; ++mi) {
#pragma unroll
    for (int q = 0; q < 4; ++q) {
      int grow = m0 + wr * 64 + mi * 16 + fq * 4 + q;
      if (grow < count) {
        unsigned sg = sgbits[ecap + grow];
        unsigned short* arow = act + (size_t)(ecap + grow) * FD + n0 + wc * 64 + fr;
#pragma unroll
        for (int ni = 0; ni < 4; ++ni) {
          int gcol = n0 + wc * 64 + ni * 16 + fr;
          float a = accU[mi][ni][q] * fmaxf(accG[mi][ni][q], 0.f);
          a = ((sg >> (gcol / 96)) & 1u) ? a : 0.f;
          arow[ni * 16] = f2bf(a);
        }
      }
    }
  }
}

// ---------------- down GEMM (bf16, async staging, work-list) + weighted scatter --------
__global__ __launch_bounds__(256, 4) void down_bf16(
    const unsigned short* __restrict__ act, const unsigned short* __restrict__ wdb,
    const int* __restrict__ tok_idx, const float* __restrict__ tok_w,
    const int* __restrict__ counts, const int* __restrict__ tlist,
    const int* __restrict__ ntiles, float* __restrict__ outF) {
  const int hw = blockIdx.x;
  const int idx = (hw & 7) * (DNGRID / 8) + (hw >> 3);
  const int ti = idx >> 4, nb = idx & 15;
  if (ti >= ntiles[0]) return;
  const int entry = tlist[ti];
  const int e = entry >> 8;
  const int m0 = (entry & 255) << 7;
  const int n0 = nb * 128;
  const int count = counts[e];

  __shared__ __align__(16) unsigned short As[128 * 64];
  __shared__ __align__(16) unsigned short Bs[128 * 64];

  const int tid = threadIdx.x, lane = tid & 63, wid = tid >> 6;
  const int wr = wid >> 1, wc = wid & 1;
  const int ecap = e * CAPE;

  const int srow = tid >> 3, sblk = tid & 7;
  const unsigned short *gA[4], *gB[4];
#pragma unroll
  for (int c = 0; c < 4; ++c) {
    int r = c * 32 + srow;
    int gr = m0 + r;
    if (gr > CAPE - 1) gr = CAPE - 1;  // worklist m0 can put m0+127 past region
    int swz = (sblk ^ (r & 7)) << 3;
    gA[c] = act + (size_t)(ecap + gr) * FD + swz;
    gB[c] = wdb + (size_t)(e * HD + n0 + r) * FD + swz;
  }
  unsigned short* lA = As + (tid << 3);
  unsigned short* lB = Bs + (tid << 3);

  f32x4 accD[4][4];
#pragma unroll
  for (int i = 0; i < 4; ++i)
#pragma unroll
    for (int j = 0; j < 4; ++j) accD[i][j] = (f32x4)0.f;

  const int fr = lane & 15, fq = lane >> 4;
  const int frx = (fr & 7) << 3;

  for (int kt = 0; kt < FD; kt += 64) {
    __syncthreads();
#pragma unroll
    for (int c = 0; c < 4; ++c) {
      async16(gA[c] + kt, lA + c * 2048);
      async16(gB[c] + kt, lB + c * 2048);
    }
    __syncthreads();
#pragma unroll
    for (int kk = 0; kk < 64; kk += 32) {
      short8 af[4], bb[4];
      const int kphys = (kk + fq * 8) ^ frx;
#pragma unroll
      for (int mi = 0; mi < 4; ++mi)
        af[mi] = *(const short8*)(As + ((wr * 64 + mi * 16 + fr) << 6) + kphys);
#pragma unroll
      for (int ni = 0; ni < 4; ++ni)
        bb[ni] = *(const short8*)(Bs + ((wc * 64 + ni * 16 + fr) << 6) + kphys);
#pragma unroll
      for (int mi = 0; mi < 4; ++mi)
#pragma unroll
        for (int ni = 0; ni < 4; ++ni)
          accD[mi][ni] = __builtin_amdgcn_mfma_f32_16x16x32_bf16(af[mi], bb[ni], accD[mi][ni], 0, 0, 0);
    }
  }
#pragma unroll
  for (int mi = 0; mi < 4; ++mi) {
#pragma unroll
    for (int q = 0; q < 4; ++q) {
      int grow = m0 + wr * 64 + mi * 16 + fq * 4 + q;
      if (grow < count) {
        float wgt = tok_w[ecap + grow];
        float* dst = outF + (size_t)tok_idx[ecap + grow] * HD + n0 + wc * 64 + fr;
#pragma unroll
        for (int ni = 0; ni < 4; ++ni)
          atomicAdd(dst + ni * 16, accD[mi][ni][q] * wgt);
      }
    }
  }
}

extern "C" void kernel_launch(void* const* d_in, const int* in_sizes, int n_in,
                              void* d_out, int out_size, void* d_ws, size_t ws_size,
                              hipStream_t stream) {
  const float* rin = (const float*)d_in[0];
  const float* x = (const float*)d_in[1];
  const float* w_router = (const float*)d_in[2];
  const float* w_up = (const float*)d_in[3];
  const float* w_gate = (const float*)d_in[4];
  const float* w_down = (const float*)d_in[5];
  const float* w_sg = (const float*)d_in[6];
  float* outF = (float*)d_out;
  float* top_logits = outF + (size_t)TT * HD;

  char* ws = (char*)d_ws;
  int* sel = (int*)(ws + 0);                      // 64 KB
  float* rwts = (float*)(ws + (64 << 10));        // 64 KB
  int* tidx = (int*)(ws + (192 << 10));           // 128 KB
  float* tw = (float*)(ws + (320 << 10));         // 128 KB
  unsigned* sgb = (unsigned*)(ws + (448 << 10));  // 128 KB
  int* counts = (int*)(ws + (576 << 10));
  int* tlist = (int*)(ws + (580 << 10));          // 1 KB
  int* ntiles = (int*)(ws + (584 << 10));
  float* logits = (float*)(ws + (640 << 10));     // 512 KB
  unsigned short* act = (unsigned short*)(ws + ((size_t)2 << 20));   // 48 MB
  float* wrt = (float*)(ws + ((size_t)51 << 20));                    // 256 KB
  unsigned short* xb = (unsigned short*)(ws + ((size_t)52 << 20));   // 16 MB
  unsigned short* wub = (unsigned short*)(ws + ((size_t)69 << 20));  // 96 MB
  unsigned short* wgb = wub + (size_t)NE * HD * FD;                  // 96 MB
  unsigned short* wdb = wgb + (size_t)NE * HD * FD;                  // 96 MB

  hipMemsetAsync(d_out, 0, (size_t)TT * HD * sizeof(float), stream);

  // routing front-end
  wrt_kernel<<<256, 256, 0, stream>>>(w_router, wrt);
  logits_kernel<<<TT / 16, 256, 0, stream>>>(rin, wrt, logits);
  topk_kernel<<<TT / 256, 256, 0, stream>>>(logits, top_logits, sel, rwts);
  dispatch_kernel<<<NE, 256, 0, stream>>>(sel, rwts, tidx, tw, counts);
  build_tiles_kernel<<<1, 64, 0, stream>>>(counts, tlist, ntiles);
  sgate_kernel<<<dim3(CAPE / 128, NE), 256, 0, stream>>>(rin, w_sg, tidx, counts, sgb);

  // bf16 conversion prepasses
  cvt_x_kernel<<<(TT * HD) / (256 * 8), 256, 0, stream>>>(x, xb);
  transpose_cvt_kernel<<<dim3(HD / 64, FD / 64, NE), 256, 0, stream>>>(w_up, wub, HD, FD);
  transpose_cvt_kernel<<<dim3(HD / 64, FD / 64, NE), 256, 0, stream>>>(w_gate, wgb, HD, FD);
  transpose_cvt_kernel<<<dim3(FD / 64, HD / 64, NE), 256, 0, stream>>>(w_down, wdb, FD, HD);

  // expert GEMMs (work-list balanced)
  up_gate_bf16<<<UPGRID, 256, 0, stream>>>(xb, wub, wgb, tidx, counts, sgb, tlist, ntiles, act);
  down_bf16<<<DNGRID, 256, 0, stream>>>(act, wdb, tidx, tw, counts, tlist, ntiles, outF);
}

// Round 5
// 621.403 us; speedup vs baseline: 1.6520x; 1.6520x over previous
//
#include <hip/hip_runtime.h>

#define TT 4096
#define HD 2048
#define FD 768
#define NE 32
#define TOPK 4
#define NSG 8
#define CAPE 1024
#define MAXTILES 160
#define UPGRID (MAXTILES * 6)
#define DNGRID (MAXTILES * 16)

typedef __attribute__((ext_vector_type(8))) short short8;
typedef __attribute__((ext_vector_type(4))) float f32x4;
typedef __attribute__((ext_vector_type(4))) unsigned short us4;
typedef __attribute__((ext_vector_type(8))) unsigned short us8;

__device__ __forceinline__ unsigned short f2bf(float f) {
  unsigned u = __builtin_bit_cast(unsigned, f);
  u += 0x7FFFu + ((u >> 16) & 1u);
  return (unsigned short)(u >> 16);
}

__device__ __forceinline__ void async16(const void* g, void* l) {
  __builtin_amdgcn_global_load_lds(
      (const __attribute__((address_space(1))) unsigned int*)g,
      (__attribute__((address_space(3))) unsigned int*)l, 16, 0, 0);
}

// ---------------- w_router [H][E] -> wrt [E][H] (fp32, tiny) ----------------
__global__ __launch_bounds__(256) void wrt_kernel(const float* __restrict__ w_router,
                                                  float* __restrict__ wrt) {
  int idx = blockIdx.x * 256 + threadIdx.x;
  int e = idx >> 11, h = idx & 2047;
  wrt[idx] = w_router[h * NE + e];
}

// ---------------- logits fp32 GEMM: [TT,HD] x [HD,NE] -> [TT,NE] ----------------
#define LSTR 68
__global__ __launch_bounds__(256) void logits_kernel(
    const float* __restrict__ rin, const float* __restrict__ wrt,
    float* __restrict__ logits) {
  __shared__ float As[16 * LSTR];
  __shared__ float Bs[32 * LSTR];
  const int tid = threadIdx.x;
  const int t0 = blockIdx.x * 16;
  const int tp = tid >> 4, eg = tid & 15;
  f32x4 acc0 = (f32x4)0.f, acc1 = (f32x4)0.f;
  for (int kt = 0; kt < HD; kt += 64) {
    __syncthreads();
    {
      int row = tid >> 4, col = (tid & 15) * 4;
      *(f32x4*)&As[row * LSTR + col] =
          *(const f32x4*)&rin[(size_t)(t0 + row) * HD + kt + col];
    }
    {
      int e = tid >> 3, col = (tid & 7) * 8;
      *(f32x4*)&Bs[e * LSTR + col] = *(const f32x4*)&wrt[(size_t)e * HD + kt + col];
      *(f32x4*)&Bs[e * LSTR + col + 4] =
          *(const f32x4*)&wrt[(size_t)e * HD + kt + col + 4];
    }
    __syncthreads();
#pragma unroll
    for (int k4 = 0; k4 < 16; ++k4) {
      f32x4 a = *(const f32x4*)&As[tp * LSTR + k4 * 4];
      f32x4 b0 = *(const f32x4*)&Bs[eg * LSTR + k4 * 4];
      f32x4 b1 = *(const f32x4*)&Bs[(eg + 16) * LSTR + k4 * 4];
      acc0 += a * b0;
      acc1 += a * b1;
    }
  }
  logits[(t0 + tp) * NE + eg] = acc0[0] + acc0[1] + acc0[2] + acc0[3];
  logits[(t0 + tp) * NE + eg + 16] = acc1[0] + acc1[1] + acc1[2] + acc1[3];
}

// ---------------- top-4 + softmax per token ----------------
__global__ __launch_bounds__(256) void topk_kernel(
    const float* __restrict__ logits, float* __restrict__ top_logits,
    int* __restrict__ sel, float* __restrict__ rwts) {
  __shared__ float lg[256 * 33];
  const int tid = threadIdx.x;
  const int t0 = blockIdx.x * 256;
#pragma unroll
  for (int i = 0; i < 8; ++i) {
    int fi = tid + i * 256;
    f32x4 v = *(const f32x4*)&logits[(size_t)t0 * NE + fi * 4];
    int tok = fi >> 3, e0 = (fi & 7) * 4;
#pragma unroll
    for (int c = 0; c < 4; ++c) lg[tok * 33 + e0 + c] = v[c];
  }
  __syncthreads();
  const float* row = &lg[tid * 33];
  float val[TOPK];
  int idx[TOPK];
  unsigned used = 0;
#pragma unroll
  for (int k = 0; k < TOPK; ++k) {
    float best = -1e30f;
    int bi = 0;
    for (int e = 0; e < NE; ++e) {
      float v = row[e];
      if (!((used >> e) & 1u) && v > best) { best = v; bi = e; }
    }
    used |= 1u << bi;
    val[k] = best;
    idx[k] = bi;
  }
  float ex[TOPK], sum = 0.f;
#pragma unroll
  for (int k = 0; k < TOPK; ++k) { ex[k] = expf(val[k] - val[0]); sum += ex[k]; }
  int t = t0 + tid;
#pragma unroll
  for (int k = 0; k < TOPK; ++k) {
    top_logits[t * TOPK + k] = val[k];
    sel[t * TOPK + k] = idx[k];
    rwts[t * TOPK + k] = ex[k] / sum;
  }
}

// ---------------- dispatch: ordered compaction per expert ----------------
__global__ __launch_bounds__(256) void dispatch_kernel(
    const int* __restrict__ sel, const float* __restrict__ rwts,
    int* __restrict__ tok_idx, float* __restrict__ tok_w, int* __restrict__ counts) {
  const int e = blockIdx.x;
  __shared__ int wcnt[4];
  __shared__ int base;
  const int tid = threadIdx.x, lane = tid & 63, wid = tid >> 6;
  if (tid == 0) base = 0;
  __syncthreads();
  for (int t0 = 0; t0 < TT; t0 += 256) {
    int t = t0 + tid;
    int hitk = -1;
#pragma unroll
    for (int k = 0; k < TOPK; ++k)
      if (sel[t * TOPK + k] == e) hitk = k;
    unsigned long long m = __ballot(hitk >= 0);
    if (lane == 0) wcnt[wid] = __popcll(m);
    __syncthreads();
    int off = base;
    for (int w = 0; w < wid; ++w) off += wcnt[w];
    int pos = off + __popcll(m & ((1ULL << lane) - 1ULL));
    if (hitk >= 0 && pos < CAPE) {
      tok_idx[e * CAPE + pos] = t;
      tok_w[e * CAPE + pos] = rwts[t * TOPK + hitk];
    }
    __syncthreads();
    if (tid == 0) base += wcnt[0] + wcnt[1] + wcnt[2] + wcnt[3];
    __syncthreads();
  }
  if (tid == 0) counts[e] = base < CAPE ? base : CAPE;
}

// ---------------- tile work-list builder (deterministic order) ----------------
__global__ void build_tiles_kernel(const int* __restrict__ counts,
                                   int* __restrict__ tlist, int* __restrict__ ntiles) {
  if (threadIdx.x == 0) {
    int n = 0;
    for (int e = 0; e < NE; ++e) {
      int c = counts[e];
      int mb = (c + 127) >> 7;
      for (int m = 0; m < mb; ++m) tlist[n++] = (e << 8) | m;
    }
    ntiles[0] = n;
  }
}

// ---------------- secondary gate per (expert, slot) ----------------
__global__ __launch_bounds__(256) void sgate_kernel(
    const float* __restrict__ rin, const float* __restrict__ w_sgate,
    const int* __restrict__ tok_idx, const int* __restrict__ counts,
    unsigned* __restrict__ sgbits) {
  const int e = blockIdx.y;
  const int count = counts[e];
  const int s0 = blockIdx.x * 128;
  if (s0 >= count || count == 0) return;
  __shared__ float wsgS[2048 * 9];
  const int tid = threadIdx.x, lane = tid & 63, wid = tid >> 6;
  const float* wsg = w_sgate + (size_t)e * (HD * NSG);
#pragma unroll
  for (int p = 0; p < 8; ++p) {
    int row = p * 256 + tid;
    f32x4 v0 = *(const f32x4*)&wsg[row * 8];
    f32x4 v1 = *(const f32x4*)&wsg[row * 8 + 4];
#pragma unroll
    for (int c = 0; c < 4; ++c) {
      wsgS[row * 9 + c] = v0[c];
      wsgS[row * 9 + 4 + c] = v1[c];
    }
  }
  __syncthreads();
  const int base = s0 + wid * 32;
  for (int j = 0; j < 16; ++j) {
    int sA = base + j, sB = base + j + 16;
    if (sA >= count) break;
    int tokA = tok_idx[e * CAPE + sA];
    int tokB = tok_idx[e * CAPE + (sB < count ? sB : sA)];
    float zA[8], zB[8];
#pragma unroll
    for (int s = 0; s < 8; ++s) { zA[s] = 0.f; zB[s] = 0.f; }
    const float* rAp = rin + (size_t)tokA * HD;
    const float* rBp = rin + (size_t)tokB * HD;
#pragma unroll 4
    for (int i = 0; i < 32; ++i) {
      int h = lane + 64 * i;
      float rA = rAp[h];
      float rB = rBp[h];
#pragma unroll
      for (int s = 0; s < 8; ++s) {
        float w = wsgS[h * 9 + s];
        zA[s] += rA * w;
        zB[s] += rB * w;
      }
    }
#pragma unroll
    for (int s = 0; s < 8; ++s) {
#pragma unroll
      for (int d = 1; d < 64; d <<= 1) {
        zA[s] += __shfl_xor(zA[s], d);
        zB[s] += __shfl_xor(zB[s], d);
      }
    }
    if (lane == 0) {
      unsigned bA = 0, bB = 0;
#pragma unroll
      for (int s = 0; s < 8; ++s) {
        bA |= ((unsigned)(zA[s] > 0.f)) << s;
        bB |= ((unsigned)(zB[s] > 0.f)) << s;
      }
      sgbits[e * CAPE + sA] = bA;
      if (sB < count) sgbits[e * CAPE + sB] = bB;
    }
  }
}

// ---------------- prepass: x fp32 -> bf16 ----------------
__global__ __launch_bounds__(256) void cvt_x_kernel(const float* __restrict__ x,
                                                    unsigned short* __restrict__ xb) {
  size_t i = ((size_t)blockIdx.x * 256 + threadIdx.x) * 8;
  float4 a = *(const float4*)(x + i);
  float4 b = *(const float4*)(x + i + 4);
  us8 o = {f2bf(a.x), f2bf(a.y), f2bf(a.z), f2bf(a.w),
           f2bf(b.x), f2bf(b.y), f2bf(b.z), f2bf(b.w)};
  *(us8*)(xb + i) = o;
}

// ---------------- prepass: per-expert transpose+convert in[R][C] f32 -> out[C][R] bf16 ---
__global__ __launch_bounds__(256) void transpose_cvt_kernel(
    const float* __restrict__ in, unsigned short* __restrict__ out, int R, int C) {
  const int e = blockIdx.z;
  const int r0 = blockIdx.x * 64, c0 = blockIdx.y * 64;
  __shared__ float t[64][65];
  const int tid = threadIdx.x;
  const float* inp = in + (size_t)e * R * C;
  {
    const int row = tid >> 4, col4 = (tid & 15) << 2;
#pragma unroll
    for (int p = 0; p < 4; ++p) {
      float4 v = *(const float4*)(inp + (size_t)(r0 + p * 16 + row) * C + c0 + col4);
      t[p * 16 + row][col4 + 0] = v.x;
      t[p * 16 + row][col4 + 1] = v.y;
      t[p * 16 + row][col4 + 2] = v.z;
      t[p * 16 + row][col4 + 3] = v.w;
    }
  }
  __syncthreads();
  {
    const int c = tid >> 2, j = tid & 3;
    us8 o0, o1;
#pragma unroll
    for (int i = 0; i < 8; ++i) o0[i] = f2bf(t[j * 16 + i][c]);
#pragma unroll
    for (int i = 0; i < 8; ++i) o1[i] = f2bf(t[j * 16 + 8 + i][c]);
    unsigned short* op = out + (size_t)e * R * C + (size_t)(c0 + c) * R + r0 + j * 16;
    *(us8*)op = o0;
    *(us8*)(op + 8) = o1;
  }
}

// ---------------- up/gate GEMM (bf16, async staging, work-list) ----------------
// (256,2): ~236 total regs/wave (108 VGPR + 128 acc) needs the 256-reg cap.
// (256,3) caps at ~170 -> spills accumulators to scratch (round-4 regression).
__global__ __launch_bounds__(256, 2) void up_gate_bf16(
    const unsigned short* __restrict__ xb, const unsigned short* __restrict__ wub,
    const unsigned short* __restrict__ wgb, const int* __restrict__ tok_idx,
    const int* __restrict__ counts, const unsigned* __restrict__ sgbits,
    const int* __restrict__ tlist, const int* __restrict__ ntiles,
    unsigned short* __restrict__ act) {
  // XCD-chunk swizzle: keep a tile's 6 n-blocks on one XCD
  const int hw = blockIdx.x;
  const int idx = (hw & 7) * (UPGRID / 8) + (hw >> 3);
  const int ti = idx / 6, nb = idx - ti * 6;
  if (ti >= ntiles[0]) return;
  const int entry = tlist[ti];
  const int e = entry >> 8;
  const int m0 = (entry & 255) << 7;
  const int n0 = nb * 128;
  const int count = counts[e];

  __shared__ __align__(16) unsigned short As[128 * 64];
  __shared__ __align__(16) unsigned short Bu[128 * 64];
  __shared__ __align__(16) unsigned short Bg[128 * 64];

  const int tid = threadIdx.x, lane = tid & 63, wid = tid >> 6;
  const int wr = wid >> 1, wc = wid & 1;
  const int ecap = e * CAPE;

  const int srow = tid >> 3, sblk = tid & 7;
  const unsigned short *gA[4], *gU[4], *gG[4];
#pragma unroll
  for (int c = 0; c < 4; ++c) {
    int r = c * 32 + srow;
    int gm = m0 + r;
    int gc = gm < count ? gm : count - 1;
    int swz = (sblk ^ (r & 7)) << 3;
    gA[c] = xb + (size_t)tok_idx[ecap + gc] * HD + swz;
    gU[c] = wub + (size_t)(e * FD + n0 + r) * HD + swz;
    gG[c] = wgb + (size_t)(e * FD + n0 + r) * HD + swz;
  }
  unsigned short* lA = As + (tid << 3);
  unsigned short* lU = Bu + (tid << 3);
  unsigned short* lG = Bg + (tid << 3);

  f32x4 accU[4][4], accG[4][4];
#pragma unroll
  for (int i = 0; i < 4; ++i)
#pragma unroll
    for (int j = 0; j < 4; ++j) { accU[i][j] = (f32x4)0.f; accG[i][j] = (f32x4)0.f; }

  const int fr = lane & 15, fq = lane >> 4;
  const int frx = (fr & 7) << 3;

  for (int kt = 0; kt < HD; kt += 64) {
    __syncthreads();
#pragma unroll
    for (int c = 0; c < 4; ++c) {
      async16(gA[c] + kt, lA + c * 2048);
      async16(gU[c] + kt, lU + c * 2048);
      async16(gG[c] + kt, lG + c * 2048);
    }
    __syncthreads();
#pragma unroll
    for (int kk = 0; kk < 64; kk += 32) {
      short8 af[4], bu[4], bg[4];
      const int kphys = (kk + fq * 8) ^ frx;
#pragma unroll
      for (int mi = 0; mi < 4; ++mi)
        af[mi] = *(const short8*)(As + ((wr * 64 + mi * 16 + fr) << 6) + kphys);
#pragma unroll
      for (int ni = 0; ni < 4; ++ni) {
        bu[ni] = *(const short8*)(Bu + ((wc * 64 + ni * 16 + fr) << 6) + kphys);
        bg[ni] = *(const short8*)(Bg + ((wc * 64 + ni * 16 + fr) << 6) + kphys);
      }
#pragma unroll
      for (int mi = 0; mi < 4; ++mi)
#pragma unroll
        for (int ni = 0; ni < 4; ++ni) {
          accU[mi][ni] = __builtin_amdgcn_mfma_f32_16x16x32_bf16(af[mi], bu[ni], accU[mi][ni], 0, 0, 0);
          accG[mi][ni] = __builtin_amdgcn_mfma_f32_16x16x32_bf16(af[mi], bg[ni], accG[mi][ni], 0, 0, 0);
        }
    }
  }
#pragma unroll
  for (int mi = 0; mi < 4; ++mi) {
#pragma unroll
    for (int q = 0; q < 4; ++q) {
      int grow = m0 + wr * 64 + mi * 16 + fq * 4 + q;
      if (grow < count) {
        unsigned sg = sgbits[ecap + grow];
        unsigned short* arow = act + (size_t)(ecap + grow) * FD + n0 + wc * 64 + fr;
#pragma unroll
        for (int ni = 0; ni < 4; ++ni) {
          int gcol = n0 + wc * 64 + ni * 16 + fr;
          float a = accU[mi][ni][q] * fmaxf(accG[mi][ni][q], 0.f);
          a = ((sg >> (gcol / 96)) & 1u) ? a : 0.f;
          arow[ni * 16] = f2bf(a);
        }
      }
    }
  }
}

// ---------------- down GEMM (bf16, async staging, work-list) + weighted scatter --------
// (256,3): ~148 regs/wave fits the 170 cap; (256,4) cap 128 spills (round-4 regression).
__global__ __launch_bounds__(256, 3) void down_bf16(
    const unsigned short* __restrict__ act, const unsigned short* __restrict__ wdb,
    const int* __restrict__ tok_idx, const float* __restrict__ tok_w,
    const int* __restrict__ counts, const int* __restrict__ tlist,
    const int* __restrict__ ntiles, float* __restrict__ outF) {
  const int hw = blockIdx.x;
  const int idx = (hw & 7) * (DNGRID / 8) + (hw >> 3);
  const int ti = idx >> 4, nb = idx & 15;
  if (ti >= ntiles[0]) return;
  const int entry = tlist[ti];
  const int e = entry >> 8;
  const int m0 = (entry & 255) << 7;
  const int n0 = nb * 128;
  const int count = counts[e];

  __shared__ __align__(16) unsigned short As[128 * 64];
  __shared__ __align__(16) unsigned short Bs[128 * 64];

  const int tid = threadIdx.x, lane = tid & 63, wid = tid >> 6;
  const int wr = wid >> 1, wc = wid & 1;
  const int ecap = e * CAPE;

  const int srow = tid >> 3, sblk = tid & 7;
  const unsigned short *gA[4], *gB[4];
#pragma unroll
  for (int c = 0; c < 4; ++c) {
    int r = c * 32 + srow;
    int gr = m0 + r;
    if (gr > CAPE - 1) gr = CAPE - 1;
    int swz = (sblk ^ (r & 7)) << 3;
    gA[c] = act + (size_t)(ecap + gr) * FD + swz;
    gB[c] = wdb + (size_t)(e * HD + n0 + r) * FD + swz;
  }
  unsigned short* lA = As + (tid << 3);
  unsigned short* lB = Bs + (tid << 3);

  f32x4 accD[4][4];
#pragma unroll
  for (int i = 0; i < 4; ++i)
#pragma unroll
    for (int j = 0; j < 4; ++j) accD[i][j] = (f32x4)0.f;

  const int fr = lane & 15, fq = lane >> 4;
  const int frx = (fr & 7) << 3;

  for (int kt = 0; kt < FD; kt += 64) {
    __syncthreads();
#pragma unroll
    for (int c = 0; c < 4; ++c) {
      async16(gA[c] + kt, lA + c * 2048);
      async16(gB[c] + kt, lB + c * 2048);
    }
    __syncthreads();
#pragma unroll
    for (int kk = 0; kk < 64; kk += 32) {
      short8 af[4], bb[4];
      const int kphys = (kk + fq * 8) ^ frx;
#pragma unroll
      for (int mi = 0; mi < 4; ++mi)
        af[mi] = *(const short8*)(As + ((wr * 64 + mi * 16 + fr) << 6) + kphys);
#pragma unroll
      for (int ni = 0; ni < 4; ++ni)
        bb[ni] = *(const short8*)(Bs + ((wc * 64 + ni * 16 + fr) << 6) + kphys);
#pragma unroll
      for (int mi = 0; mi < 4; ++mi)
#pragma unroll
        for (int ni = 0; ni < 4; ++ni)
          accD[mi][ni] = __builtin_amdgcn_mfma_f32_16x16x32_bf16(af[mi], bb[ni], accD[mi][ni], 0, 0, 0);
    }
  }
#pragma unroll
  for (int mi = 0; mi < 4; ++mi) {
#pragma unroll
    for (int q = 0; q < 4; ++q) {
      int grow = m0 + wr * 64 + mi * 16 + fq * 4 + q;
      if (grow < count) {
        float wgt = tok_w[ecap + grow];
        float* dst = outF + (size_t)tok_idx[ecap + grow] * HD + n0 + wc * 64 + fr;
#pragma unroll
        for (int ni = 0; ni < 4; ++ni)
          atomicAdd(dst + ni * 16, accD[mi][ni][q] * wgt);
      }
    }
  }
}

extern "C" void kernel_launch(void* const* d_in, const int* in_sizes, int n_in,
                              void* d_out, int out_size, void* d_ws, size_t ws_size,
                              hipStream_t stream) {
  const float* rin = (const float*)d_in[0];
  const float* x = (const float*)d_in[1];
  const float* w_router = (const float*)d_in[2];
  const float* w_up = (const float*)d_in[3];
  const float* w_gate = (const float*)d_in[4];
  const float* w_down = (const float*)d_in[5];
  const float* w_sg = (const float*)d_in[6];
  float* outF = (float*)d_out;
  float* top_logits = outF + (size_t)TT * HD;

  char* ws = (char*)d_ws;
  int* sel = (int*)(ws + 0);                      // 64 KB
  float* rwts = (float*)(ws + (64 << 10));        // 64 KB
  int* tidx = (int*)(ws + (192 << 10));           // 128 KB
  float* tw = (float*)(ws + (320 << 10));         // 128 KB
  unsigned* sgb = (unsigned*)(ws + (448 << 10));  // 128 KB
  int* counts = (int*)(ws + (576 << 10));
  int* tlist = (int*)(ws + (580 << 10));          // 1 KB
  int* ntiles = (int*)(ws + (584 << 10));
  float* logits = (float*)(ws + (640 << 10));     // 512 KB
  unsigned short* act = (unsigned short*)(ws + ((size_t)2 << 20));   // 48 MB
  float* wrt = (float*)(ws + ((size_t)51 << 20));                    // 256 KB
  unsigned short* xb = (unsigned short*)(ws + ((size_t)52 << 20));   // 16 MB
  unsigned short* wub = (unsigned short*)(ws + ((size_t)69 << 20));  // 96 MB
  unsigned short* wgb = wub + (size_t)NE * HD * FD;                  // 96 MB
  unsigned short* wdb = wgb + (size_t)NE * HD * FD;                  // 96 MB

  hipMemsetAsync(d_out, 0, (size_t)TT * HD * sizeof(float), stream);

  // routing front-end
  wrt_kernel<<<256, 256, 0, stream>>>(w_router, wrt);
  logits_kernel<<<TT / 16, 256, 0, stream>>>(rin, wrt, logits);
  topk_kernel<<<TT / 256, 256, 0, stream>>>(logits, top_logits, sel, rwts);
  dispatch_kernel<<<NE, 256, 0, stream>>>(sel, rwts, tidx, tw, counts);
  build_tiles_kernel<<<1, 64, 0, stream>>>(counts, tlist, ntiles);
  sgate_kernel<<<dim3(CAPE / 128, NE), 256, 0, stream>>>(rin, w_sg, tidx, counts, sgb);

  // bf16 conversion prepasses
  cvt_x_kernel<<<(TT * HD) / (256 * 8), 256, 0, stream>>>(x, xb);
  transpose_cvt_kernel<<<dim3(HD / 64, FD / 64, NE), 256, 0, stream>>>(w_up, wub, HD, FD);
  transpose_cvt_kernel<<<dim3(HD / 64, FD / 64, NE), 256, 0, stream>>>(w_gate, wgb, HD, FD);
  transpose_cvt_kernel<<<dim3(FD / 64, HD / 64, NE), 256, 0, stream>>>(w_down, wdb, FD, HD);

  // expert GEMMs (work-list balanced)
  up_gate_bf16<<<UPGRID, 256, 0, stream>>>(xb, wub, wgb, tidx, counts, sgb, tlist, ntiles, act);
  down_bf16<<<DNGRID, 256, 0, stream>>>(act, wdb, tidx, tw, counts, tlist, ntiles, outF);
}

// Round 6
// 574.031 us; speedup vs baseline: 1.7883x; 1.0825x over previous
//
#include <hip/hip_runtime.h>

#define TT 4096
#define HD 2048
#define FD 768
#define NE 32
#define TOPK 4
#define NSG 8
#define CAPE 1024
#define MAXTILES 160
#define UPGRID (MAXTILES * 12)
#define DNGRID (MAXTILES * 16)

typedef __attribute__((ext_vector_type(8))) short short8;
typedef __attribute__((ext_vector_type(4))) float f32x4;
typedef __attribute__((ext_vector_type(4))) unsigned short us4;
typedef __attribute__((ext_vector_type(8))) unsigned short us8;

__device__ __forceinline__ unsigned short f2bf(float f) {
  unsigned u = __builtin_bit_cast(unsigned, f);
  u += 0x7FFFu + ((u >> 16) & 1u);
  return (unsigned short)(u >> 16);
}
__device__ __forceinline__ float bf2f(unsigned short b) {
  return __builtin_bit_cast(float, (unsigned)b << 16);
}

__device__ __forceinline__ void async16(const void* g, void* l) {
  __builtin_amdgcn_global_load_lds(
      (const __attribute__((address_space(1))) unsigned int*)g,
      (__attribute__((address_space(3))) unsigned int*)l, 16, 0, 0);
}

// ---------------- w_router [H][E] -> wrt [E][H] (fp32, tiny) ----------------
__global__ __launch_bounds__(256) void wrt_kernel(const float* __restrict__ w_router,
                                                  float* __restrict__ wrt) {
  int idx = blockIdx.x * 256 + threadIdx.x;
  int e = idx >> 11, h = idx & 2047;
  wrt[idx] = w_router[h * NE + e];
}

// ---------------- logits fp32 GEMM: [TT,HD] x [HD,NE] -> [TT,NE] ----------------
#define LSTR 68
__global__ __launch_bounds__(256) void logits_kernel(
    const float* __restrict__ rin, const float* __restrict__ wrt,
    float* __restrict__ logits) {
  __shared__ float As[16 * LSTR];
  __shared__ float Bs[32 * LSTR];
  const int tid = threadIdx.x;
  const int t0 = blockIdx.x * 16;
  const int tp = tid >> 4, eg = tid & 15;
  f32x4 acc0 = (f32x4)0.f, acc1 = (f32x4)0.f;
  for (int kt = 0; kt < HD; kt += 64) {
    __syncthreads();
    {
      int row = tid >> 4, col = (tid & 15) * 4;
      *(f32x4*)&As[row * LSTR + col] =
          *(const f32x4*)&rin[(size_t)(t0 + row) * HD + kt + col];
    }
    {
      int e = tid >> 3, col = (tid & 7) * 8;
      *(f32x4*)&Bs[e * LSTR + col] = *(const f32x4*)&wrt[(size_t)e * HD + kt + col];
      *(f32x4*)&Bs[e * LSTR + col + 4] =
          *(const f32x4*)&wrt[(size_t)e * HD + kt + col + 4];
    }
    __syncthreads();
#pragma unroll
    for (int k4 = 0; k4 < 16; ++k4) {
      f32x4 a = *(const f32x4*)&As[tp * LSTR + k4 * 4];
      f32x4 b0 = *(const f32x4*)&Bs[eg * LSTR + k4 * 4];
      f32x4 b1 = *(const f32x4*)&Bs[(eg + 16) * LSTR + k4 * 4];
      acc0 += a * b0;
      acc1 += a * b1;
    }
  }
  logits[(t0 + tp) * NE + eg] = acc0[0] + acc0[1] + acc0[2] + acc0[3];
  logits[(t0 + tp) * NE + eg + 16] = acc1[0] + acc1[1] + acc1[2] + acc1[3];
}

// ---------------- top-4 + softmax per token ----------------
__global__ __launch_bounds__(256) void topk_kernel(
    const float* __restrict__ logits, float* __restrict__ top_logits,
    int* __restrict__ sel, float* __restrict__ rwts) {
  __shared__ float lg[256 * 33];
  const int tid = threadIdx.x;
  const int t0 = blockIdx.x * 256;
#pragma unroll
  for (int i = 0; i < 8; ++i) {
    int fi = tid + i * 256;
    f32x4 v = *(const f32x4*)&logits[(size_t)t0 * NE + fi * 4];
    int tok = fi >> 3, e0 = (fi & 7) * 4;
#pragma unroll
    for (int c = 0; c < 4; ++c) lg[tok * 33 + e0 + c] = v[c];
  }
  __syncthreads();
  const float* row = &lg[tid * 33];
  float val[TOPK];
  int idx[TOPK];
  unsigned used = 0;
#pragma unroll
  for (int k = 0; k < TOPK; ++k) {
    float best = -1e30f;
    int bi = 0;
    for (int e = 0; e < NE; ++e) {
      float v = row[e];
      if (!((used >> e) & 1u) && v > best) { best = v; bi = e; }
    }
    used |= 1u << bi;
    val[k] = best;
    idx[k] = bi;
  }
  float ex[TOPK], sum = 0.f;
#pragma unroll
  for (int k = 0; k < TOPK; ++k) { ex[k] = expf(val[k] - val[0]); sum += ex[k]; }
  int t = t0 + tid;
#pragma unroll
  for (int k = 0; k < TOPK; ++k) {
    top_logits[t * TOPK + k] = val[k];
    sel[t * TOPK + k] = idx[k];
    rwts[t * TOPK + k] = ex[k] / sum;
  }
}

// ---------------- dispatch: ordered compaction per expert + slot map ----------------
__global__ __launch_bounds__(256) void dispatch_kernel(
    const int* __restrict__ sel, const float* __restrict__ rwts,
    int* __restrict__ tok_idx, float* __restrict__ tok_w, int* __restrict__ counts,
    int* __restrict__ slotmap) {
  const int e = blockIdx.x;
  __shared__ int wcnt[4];
  __shared__ int base;
  const int tid = threadIdx.x, lane = tid & 63, wid = tid >> 6;
  if (tid == 0) base = 0;
  __syncthreads();
  for (int t0 = 0; t0 < TT; t0 += 256) {
    int t = t0 + tid;
    int hitk = -1;
#pragma unroll
    for (int k = 0; k < TOPK; ++k)
      if (sel[t * TOPK + k] == e) hitk = k;
    unsigned long long m = __ballot(hitk >= 0);
    if (lane == 0) wcnt[wid] = __popcll(m);
    __syncthreads();
    int off = base;
    for (int w = 0; w < wid; ++w) off += wcnt[w];
    int pos = off + __popcll(m & ((1ULL << lane) - 1ULL));
    if (hitk >= 0) {
      if (pos < CAPE) {
        tok_idx[e * CAPE + pos] = t;
        tok_w[e * CAPE + pos] = rwts[t * TOPK + hitk];
        slotmap[t * TOPK + hitk] = e * CAPE + pos;
      } else {
        slotmap[t * TOPK + hitk] = -1;  // dropped (over capacity)
      }
    }
    __syncthreads();
    if (tid == 0) base += wcnt[0] + wcnt[1] + wcnt[2] + wcnt[3];
    __syncthreads();
  }
  if (tid == 0) counts[e] = base < CAPE ? base : CAPE;
}

// ---------------- tile work-list builder (deterministic order) ----------------
__global__ void build_tiles_kernel(const int* __restrict__ counts,
                                   int* __restrict__ tlist, int* __restrict__ ntiles) {
  if (threadIdx.x == 0) {
    int n = 0;
    for (int e = 0; e < NE; ++e) {
      int c = counts[e];
      int mb = (c + 127) >> 7;
      for (int m = 0; m < mb; ++m) tlist[n++] = (e << 8) | m;
    }
    ntiles[0] = n;
  }
}

// ---------------- secondary gate per (expert, slot) ----------------
__global__ __launch_bounds__(256) void sgate_kernel(
    const float* __restrict__ rin, const float* __restrict__ w_sgate,
    const int* __restrict__ tok_idx, const int* __restrict__ counts,
    unsigned* __restrict__ sgbits) {
  const int e = blockIdx.y;
  const int count = counts[e];
  const int s0 = blockIdx.x * 128;
  if (s0 >= count || count == 0) return;
  __shared__ float wsgS[2048 * 9];
  const int tid = threadIdx.x, lane = tid & 63, wid = tid >> 6;
  const float* wsg = w_sgate + (size_t)e * (HD * NSG);
#pragma unroll
  for (int p = 0; p < 8; ++p) {
    int row = p * 256 + tid;
    f32x4 v0 = *(const f32x4*)&wsg[row * 8];
    f32x4 v1 = *(const f32x4*)&wsg[row * 8 + 4];
#pragma unroll
    for (int c = 0; c < 4; ++c) {
      wsgS[row * 9 + c] = v0[c];
      wsgS[row * 9 + 4 + c] = v1[c];
    }
  }
  __syncthreads();
  const int base = s0 + wid * 32;
  for (int j = 0; j < 16; ++j) {
    int sA = base + j, sB = base + j + 16;
    if (sA >= count) break;
    int tokA = tok_idx[e * CAPE + sA];
    int tokB = tok_idx[e * CAPE + (sB < count ? sB : sA)];
    float zA[8], zB[8];
#pragma unroll
    for (int s = 0; s < 8; ++s) { zA[s] = 0.f; zB[s] = 0.f; }
    const float* rAp = rin + (size_t)tokA * HD;
    const float* rBp = rin + (size_t)tokB * HD;
#pragma unroll 4
    for (int i = 0; i < 32; ++i) {
      int h = lane + 64 * i;
      float rA = rAp[h];
      float rB = rBp[h];
#pragma unroll
      for (int s = 0; s < 8; ++s) {
        float w = wsgS[h * 9 + s];
        zA[s] += rA * w;
        zB[s] += rB * w;
      }
    }
#pragma unroll
    for (int s = 0; s < 8; ++s) {
#pragma unroll
      for (int d = 1; d < 64; d <<= 1) {
        zA[s] += __shfl_xor(zA[s], d);
        zB[s] += __shfl_xor(zB[s], d);
      }
    }
    if (lane == 0) {
      unsigned bA = 0, bB = 0;
#pragma unroll
      for (int s = 0; s < 8; ++s) {
        bA |= ((unsigned)(zA[s] > 0.f)) << s;
        bB |= ((unsigned)(zB[s] > 0.f)) << s;
      }
      sgbits[e * CAPE + sA] = bA;
      if (sB < count) sgbits[e * CAPE + sB] = bB;
    }
  }
}

// ---------------- prepass: x fp32 -> bf16 ----------------
__global__ __launch_bounds__(256) void cvt_x_kernel(const float* __restrict__ x,
                                                    unsigned short* __restrict__ xb) {
  size_t i = ((size_t)blockIdx.x * 256 + threadIdx.x) * 8;
  float4 a = *(const float4*)(x + i);
  float4 b = *(const float4*)(x + i + 4);
  us8 o = {f2bf(a.x), f2bf(a.y), f2bf(a.z), f2bf(a.w),
           f2bf(b.x), f2bf(b.y), f2bf(b.z), f2bf(b.w)};
  *(us8*)(xb + i) = o;
}

// ---------------- prepass: per-expert transpose+convert in[R][C] f32 -> out[C][R] bf16 ---
__global__ __launch_bounds__(256) void transpose_cvt_kernel(
    const float* __restrict__ in, unsigned short* __restrict__ out, int R, int C) {
  const int e = blockIdx.z;
  const int r0 = blockIdx.x * 64, c0 = blockIdx.y * 64;
  __shared__ float t[64][65];
  const int tid = threadIdx.x;
  const float* inp = in + (size_t)e * R * C;
  {
    const int row = tid >> 4, col4 = (tid & 15) << 2;
#pragma unroll
    for (int p = 0; p < 4; ++p) {
      float4 v = *(const float4*)(inp + (size_t)(r0 + p * 16 + row) * C + c0 + col4);
      t[p * 16 + row][col4 + 0] = v.x;
      t[p * 16 + row][col4 + 1] = v.y;
      t[p * 16 + row][col4 + 2] = v.z;
      t[p * 16 + row][col4 + 3] = v.w;
    }
  }
  __syncthreads();
  {
    const int c = tid >> 2, j = tid & 3;
    us8 o0, o1;
#pragma unroll
    for (int i = 0; i < 8; ++i) o0[i] = f2bf(t[j * 16 + i][c]);
#pragma unroll
    for (int i = 0; i < 8; ++i) o1[i] = f2bf(t[j * 16 + 8 + i][c]);
    unsigned short* op = out + (size_t)e * R * C + (size_t)(c0 + c) * R + r0 + j * 16;
    *(us8*)op = o0;
    *(us8*)(op + 8) = o1;
  }
}

// ---------------- up/gate GEMM: 128m x 64n tiles, acc 64 regs -> (256,3) no spill ------
__global__ __launch_bounds__(256, 3) void up_gate_bf16(
    const unsigned short* __restrict__ xb, const unsigned short* __restrict__ wub,
    const unsigned short* __restrict__ wgb, const int* __restrict__ tok_idx,
    const int* __restrict__ counts, const unsigned* __restrict__ sgbits,
    const int* __restrict__ tlist, const int* __restrict__ ntiles,
    unsigned short* __restrict__ act) {
  // XCD-chunk swizzle: keep a tile's 12 n-blocks on one XCD
  const int hw = blockIdx.x;
  const int idx = (hw & 7) * (UPGRID / 8) + (hw >> 3);
  const int ti = idx / 12, nb = idx - ti * 12;
  if (ti >= ntiles[0]) return;
  const int entry = tlist[ti];
  const int e = entry >> 8;
  const int m0 = (entry & 255) << 7;
  const int n0 = nb * 64;
  const int count = counts[e];

  __shared__ __align__(16) unsigned short As[128 * 64];
  __shared__ __align__(16) unsigned short Bu[64 * 64];
  __shared__ __align__(16) unsigned short Bg[64 * 64];

  const int tid = threadIdx.x, lane = tid & 63, wid = tid >> 6;
  const int wr = wid >> 1, wc = wid & 1;  // 2x2 waves over (128m, 64n)
  const int ecap = e * CAPE;

  const int srow = tid >> 3, sblk = tid & 7;
  const unsigned short *gA[4], *gU[2], *gG[2];
#pragma unroll
  for (int c = 0; c < 4; ++c) {
    int r = c * 32 + srow;
    int gm = m0 + r;
    int gc = gm < count ? gm : count - 1;
    int swz = (sblk ^ (r & 7)) << 3;
    gA[c] = xb + (size_t)tok_idx[ecap + gc] * HD + swz;
  }
#pragma unroll
  for (int c = 0; c < 2; ++c) {
    int r = c * 32 + srow;
    int swz = (sblk ^ (r & 7)) << 3;
    gU[c] = wub + (size_t)(e * FD + n0 + r) * HD + swz;
    gG[c] = wgb + (size_t)(e * FD + n0 + r) * HD + swz;
  }
  unsigned short* lA = As + (tid << 3);
  unsigned short* lU = Bu + (tid << 3);
  unsigned short* lG = Bg + (tid << 3);

  f32x4 accU[4][2], accG[4][2];
#pragma unroll
  for (int i = 0; i < 4; ++i)
#pragma unroll
    for (int j = 0; j < 2; ++j) { accU[i][j] = (f32x4)0.f; accG[i][j] = (f32x4)0.f; }

  const int fr = lane & 15, fq = lane >> 4;
  const int frx = (fr & 7) << 3;

  for (int kt = 0; kt < HD; kt += 64) {
    __syncthreads();
#pragma unroll
    for (int c = 0; c < 4; ++c) async16(gA[c] + kt, lA + c * 2048);
#pragma unroll
    for (int c = 0; c < 2; ++c) {
      async16(gU[c] + kt, lU + c * 2048);
      async16(gG[c] + kt, lG + c * 2048);
    }
    __syncthreads();
#pragma unroll
    for (int kk = 0; kk < 64; kk += 32) {
      short8 af[4], bu[2], bg[2];
      const int kphys = (kk + fq * 8) ^ frx;
#pragma unroll
      for (int mi = 0; mi < 4; ++mi)
        af[mi] = *(const short8*)(As + ((wr * 64 + mi * 16 + fr) << 6) + kphys);
#pragma unroll
      for (int ni = 0; ni < 2; ++ni) {
        bu[ni] = *(const short8*)(Bu + ((wc * 32 + ni * 16 + fr) << 6) + kphys);
        bg[ni] = *(const short8*)(Bg + ((wc * 32 + ni * 16 + fr) << 6) + kphys);
      }
#pragma unroll
      for (int mi = 0; mi < 4; ++mi)
#pragma unroll
        for (int ni = 0; ni < 2; ++ni) {
          accU[mi][ni] = __builtin_amdgcn_mfma_f32_16x16x32_bf16(af[mi], bu[ni], accU[mi][ni], 0, 0, 0);
          accG[mi][ni] = __builtin_amdgcn_mfma_f32_16x16x32_bf16(af[mi], bg[ni], accG[mi][ni], 0, 0, 0);
        }
    }
  }
#pragma unroll
  for (int mi = 0; mi < 4; ++mi) {
#pragma unroll
    for (int q = 0; q < 4; ++q) {
      int grow = m0 + wr * 64 + mi * 16 + fq * 4 + q;
      if (grow < count) {
        unsigned sg = sgbits[ecap + grow];
        unsigned short* arow = act + (size_t)(ecap + grow) * FD + n0 + wc * 32 + fr;
#pragma unroll
        for (int ni = 0; ni < 2; ++ni) {
          int gcol = n0 + wc * 32 + ni * 16 + fr;
          float a = accU[mi][ni][q] * fmaxf(accG[mi][ni][q], 0.f);
          a = ((sg >> (gcol / 96)) & 1u) ? a : 0.f;
          arow[ni * 16] = f2bf(a);
        }
      }
    }
  }
}

// ---------------- down GEMM -> per-slot bf16 rows (no atomics) ----------------
__global__ __launch_bounds__(256, 3) void down_bf16(
    const unsigned short* __restrict__ act, const unsigned short* __restrict__ wdb,
    const int* __restrict__ counts, const int* __restrict__ tlist,
    const int* __restrict__ ntiles, unsigned short* __restrict__ act_dn) {
  const int hw = blockIdx.x;
  const int idx = (hw & 7) * (DNGRID / 8) + (hw >> 3);
  const int ti = idx >> 4, nb = idx & 15;
  if (ti >= ntiles[0]) return;
  const int entry = tlist[ti];
  const int e = entry >> 8;
  const int m0 = (entry & 255) << 7;
  const int n0 = nb * 128;
  const int count = counts[e];

  __shared__ __align__(16) unsigned short As[128 * 64];
  __shared__ __align__(16) unsigned short Bs[128 * 64];

  const int tid = threadIdx.x, lane = tid & 63, wid = tid >> 6;
  const int wr = wid >> 1, wc = wid & 1;
  const int ecap = e * CAPE;

  const int srow = tid >> 3, sblk = tid & 7;
  const unsigned short *gA[4], *gB[4];
#pragma unroll
  for (int c = 0; c < 4; ++c) {
    int r = c * 32 + srow;
    int gr = m0 + r;
    if (gr > CAPE - 1) gr = CAPE - 1;
    int swz = (sblk ^ (r & 7)) << 3;
    gA[c] = act + (size_t)(ecap + gr) * FD + swz;
    gB[c] = wdb + (size_t)(e * HD + n0 + r) * FD + swz;
  }
  unsigned short* lA = As + (tid << 3);
  unsigned short* lB = Bs + (tid << 3);

  f32x4 accD[4][4];
#pragma unroll
  for (int i = 0; i < 4; ++i)
#pragma unroll
    for (int j = 0; j < 4; ++j) accD[i][j] = (f32x4)0.f;

  const int fr = lane & 15, fq = lane >> 4;
  const int frx = (fr & 7) << 3;

  for (int kt = 0; kt < FD; kt += 64) {
    __syncthreads();
#pragma unroll
    for (int c = 0; c < 4; ++c) {
      async16(gA[c] + kt, lA + c * 2048);
      async16(gB[c] + kt, lB + c * 2048);
    }
    __syncthreads();
#pragma unroll
    for (int kk = 0; kk < 64; kk += 32) {
      short8 af[4], bb[4];
      const int kphys = (kk + fq * 8) ^ frx;
#pragma unroll
      for (int mi = 0; mi < 4; ++mi)
        af[mi] = *(const short8*)(As + ((wr * 64 + mi * 16 + fr) << 6) + kphys);
#pragma unroll
      for (int ni = 0; ni < 4; ++ni)
        bb[ni] = *(const short8*)(Bs + ((wc * 64 + ni * 16 + fr) << 6) + kphys);
#pragma unroll
      for (int mi = 0; mi < 4; ++mi)
#pragma unroll
        for (int ni = 0; ni < 4; ++ni)
          accD[mi][ni] = __builtin_amdgcn_mfma_f32_16x16x32_bf16(af[mi], bb[ni], accD[mi][ni], 0, 0, 0);
    }
  }
#pragma unroll
  for (int mi = 0; mi < 4; ++mi) {
#pragma unroll
    for (int q = 0; q < 4; ++q) {
      int grow = m0 + wr * 64 + mi * 16 + fq * 4 + q;
      if (grow < count) {
        unsigned short* drow = act_dn + (size_t)(ecap + grow) * HD + n0 + wc * 64 + fr;
#pragma unroll
        for (int ni = 0; ni < 4; ++ni)
          drow[ni * 16] = f2bf(accD[mi][ni][q]);
      }
    }
  }
}

// ---------------- combine: out[t] = sum_k w[slot] * act_dn[slot] ----------------
__global__ __launch_bounds__(256) void combine_kernel(
    const unsigned short* __restrict__ act_dn, const float* __restrict__ tok_w,
    const int* __restrict__ slotmap, float* __restrict__ outF) {
  const int t = blockIdx.x;
  const int h = threadIdx.x * 8;
  const int4 sm = *(const int4*)(slotmap + t * TOPK);
  float acc[8];
#pragma unroll
  for (int j = 0; j < 8; ++j) acc[j] = 0.f;
  const int ss[4] = {sm.x, sm.y, sm.z, sm.w};
#pragma unroll
  for (int k = 0; k < TOPK; ++k) {
    int s = ss[k];
    if (s >= 0) {
      float w = tok_w[s];
      us8 v = *(const us8*)(act_dn + (size_t)s * HD + h);
#pragma unroll
      for (int j = 0; j < 8; ++j) acc[j] += w * bf2f(v[j]);
    }
  }
  float* op = outF + (size_t)t * HD + h;
  f32x4 o0 = {acc[0], acc[1], acc[2], acc[3]};
  f32x4 o1 = {acc[4], acc[5], acc[6], acc[7]};
  *(f32x4*)op = o0;
  *(f32x4*)(op + 4) = o1;
}

extern "C" void kernel_launch(void* const* d_in, const int* in_sizes, int n_in,
                              void* d_out, int out_size, void* d_ws, size_t ws_size,
                              hipStream_t stream) {
  const float* rin = (const float*)d_in[0];
  const float* x = (const float*)d_in[1];
  const float* w_router = (const float*)d_in[2];
  const float* w_up = (const float*)d_in[3];
  const float* w_gate = (const float*)d_in[4];
  const float* w_down = (const float*)d_in[5];
  const float* w_sg = (const float*)d_in[6];
  float* outF = (float*)d_out;
  float* top_logits = outF + (size_t)TT * HD;

  char* ws = (char*)d_ws;
  int* sel = (int*)(ws + 0);                      // 64 KB
  float* rwts = (float*)(ws + (64 << 10));        // 64 KB
  int* tidx = (int*)(ws + (192 << 10));           // 128 KB
  float* tw = (float*)(ws + (320 << 10));         // 128 KB
  unsigned* sgb = (unsigned*)(ws + (448 << 10));  // 128 KB
  int* counts = (int*)(ws + (576 << 10));
  int* tlist = (int*)(ws + (580 << 10));          // 1 KB
  int* ntiles = (int*)(ws + (584 << 10));
  float* logits = (float*)(ws + (640 << 10));     // 512 KB
  int* slotmap = (int*)(ws + (1152 << 10));       // 64 KB
  unsigned short* act = (unsigned short*)(ws + ((size_t)2 << 20));   // 48 MB
  float* wrt = (float*)(ws + ((size_t)51 << 20));                    // 256 KB
  unsigned short* xb = (unsigned short*)(ws + ((size_t)52 << 20));   // 16 MB
  unsigned short* wub = (unsigned short*)(ws + ((size_t)69 << 20));  // 96 MB
  unsigned short* wgb = wub + (size_t)NE * HD * FD;                  // 96 MB
  unsigned short* wdb = wgb + (size_t)NE * HD * FD;                  // 96 MB
  // act_dn overlays wub (dead by the time down_bf16 runs): 64 MB <= 96 MB
  unsigned short* act_dn = wub;

  // routing front-end
  wrt_kernel<<<256, 256, 0, stream>>>(w_router, wrt);
  logits_kernel<<<TT / 16, 256, 0, stream>>>(rin, wrt, logits);
  topk_kernel<<<TT / 256, 256, 0, stream>>>(logits, top_logits, sel, rwts);
  dispatch_kernel<<<NE, 256, 0, stream>>>(sel, rwts, tidx, tw, counts, slotmap);
  build_tiles_kernel<<<1, 64, 0, stream>>>(counts, tlist, ntiles);
  sgate_kernel<<<dim3(CAPE / 128, NE), 256, 0, stream>>>(rin, w_sg, tidx, counts, sgb);

  // bf16 conversion prepasses
  cvt_x_kernel<<<(TT * HD) / (256 * 8), 256, 0, stream>>>(x, xb);
  transpose_cvt_kernel<<<dim3(HD / 64, FD / 64, NE), 256, 0, stream>>>(w_up, wub, HD, FD);
  transpose_cvt_kernel<<<dim3(HD / 64, FD / 64, NE), 256, 0, stream>>>(w_gate, wgb, HD, FD);
  transpose_cvt_kernel<<<dim3(FD / 64, HD / 64, NE), 256, 0, stream>>>(w_down, wdb, FD, HD);

  // expert GEMMs (work-list balanced)
  up_gate_bf16<<<UPGRID, 256, 0, stream>>>(xb, wub, wgb, tidx, counts, sgb, tlist, ntiles, act);
  down_bf16<<<DNGRID, 256, 0, stream>>>(act, wdb, counts, tlist, ntiles, act_dn);
  combine_kernel<<<TT, 256, 0, stream>>>(act_dn, tw, slotmap, outF);
}